// Round 3
// baseline (3932.765 us; speedup 1.0000x reference)
//
#include <hip/hip_runtime.h>
#include <hip/hip_bf16.h>
#include <math.h>

constexpr int BATCH = 256;
constexpr int SEQ   = 128;
constexpr int FEAT  = 512;
constexpr int HID   = 512;
constexpr int G3    = 1536;

typedef __bf16 bf16x8 __attribute__((ext_vector_type(8)));
typedef float  f32x4  __attribute__((ext_vector_type(4)));

// ---------------------------------------------------------------------------
// fp32 -> bf16 convert (vectorized, 8/thread)
// ---------------------------------------------------------------------------
__global__ __launch_bounds__(256) void convert_bf16(
    const float* __restrict__ in, __hip_bfloat16* __restrict__ out, int n)
{
  int i = (blockIdx.x * 256 + threadIdx.x) * 8;
  if (i >= n) return;
  float4 v0 = *(const float4*)&in[i];
  float4 v1 = *(const float4*)&in[i + 4];
  __hip_bfloat16 o[8];
  o[0] = (__hip_bfloat16)v0.x; o[1] = (__hip_bfloat16)v0.y;
  o[2] = (__hip_bfloat16)v0.z; o[3] = (__hip_bfloat16)v0.w;
  o[4] = (__hip_bfloat16)v1.x; o[5] = (__hip_bfloat16)v1.y;
  o[6] = (__hip_bfloat16)v1.z; o[7] = (__hip_bfloat16)v1.w;
  *(int4*)&out[i] = *(int4*)o;
}

// ---------------------------------------------------------------------------
// transpose + convert: in[512][1536] f32 -> outT[1536][512] bf16
// ---------------------------------------------------------------------------
__global__ __launch_bounds__(256) void transpose_convert(
    const float* __restrict__ in, __hip_bfloat16* __restrict__ outT)
{
  __shared__ float tile[32][33];
  const int c0 = blockIdx.x * 32;
  const int r0 = blockIdx.y * 32;
  const int tid = threadIdx.x;
  {
    int row = tid >> 3, c4 = tid & 7;
    float4 v = *(const float4*)&in[(size_t)(r0 + row) * G3 + c0 + c4 * 4];
    tile[row][c4 * 4 + 0] = v.x;
    tile[row][c4 * 4 + 1] = v.y;
    tile[row][c4 * 4 + 2] = v.z;
    tile[row][c4 * 4 + 3] = v.w;
  }
  __syncthreads();
  {
    int rowT = tid >> 3, c4 = tid & 7;
    __hip_bfloat16 o[4];
#pragma unroll
    for (int e = 0; e < 4; ++e)
      o[e] = (__hip_bfloat16)tile[c4 * 4 + e][rowT];
    *(int2*)&outT[(size_t)(c0 + rowT) * FEAT + r0 + c4 * 4] = *(int2*)o;
  }
}

// ---------------------------------------------------------------------------
// proj: xp[m][n] (bf16) = xb[m][:] @ Wk[:, n] + bi[n]   (same as R2)
// ---------------------------------------------------------------------------
__global__ __launch_bounds__(256) void proj_mfma(
    const __hip_bfloat16* __restrict__ xb, const __hip_bfloat16* __restrict__ WkT,
    const float* __restrict__ bias, __hip_bfloat16* __restrict__ xp)
{
  __shared__ __align__(16) __hip_bfloat16 As[128][72];
  __shared__ __align__(16) __hip_bfloat16 Bs[128][72];

  const int tid = threadIdx.x;
  const int wave = tid >> 6, l = tid & 63;
  const int wm = wave >> 1, wn = wave & 1;
  const int m0 = blockIdx.y * 128;
  const int n0 = blockIdx.x * 128;
  const int lr = l & 15, lk = (l >> 4) * 8;

  f32x4 acc[4][4] = {};

  for (int k0 = 0; k0 < FEAT; k0 += 64) {
    __syncthreads();
#pragma unroll
    for (int i = 0; i < 4; ++i) {
      int q = tid + i * 256;
      int row = q >> 3, c = q & 7;
      *(int4*)&As[row][c * 8] =
          *(const int4*)&xb[(size_t)(m0 + row) * FEAT + k0 + c * 8];
    }
#pragma unroll
    for (int i = 0; i < 4; ++i) {
      int q = tid + i * 256;
      int row = q >> 3, c = q & 7;
      *(int4*)&Bs[row][c * 8] =
          *(const int4*)&WkT[(size_t)(n0 + row) * FEAT + k0 + c * 8];
    }
    __syncthreads();

#pragma unroll
    for (int ks = 0; ks < 2; ++ks) {
      bf16x8 a[4], b[4];
#pragma unroll
      for (int i = 0; i < 4; ++i)
        a[i] = *(const bf16x8*)&As[wm * 64 + i * 16 + lr][ks * 32 + lk];
#pragma unroll
      for (int j = 0; j < 4; ++j)
        b[j] = *(const bf16x8*)&Bs[wn * 64 + j * 16 + lr][ks * 32 + lk];
#pragma unroll
      for (int i = 0; i < 4; ++i)
#pragma unroll
        for (int j = 0; j < 4; ++j)
          acc[i][j] = __builtin_amdgcn_mfma_f32_16x16x32_bf16(a[i], b[j], acc[i][j], 0, 0, 0);
    }
  }

  float bv[4];
#pragma unroll
  for (int j = 0; j < 4; ++j)
    bv[j] = bias[n0 + wn * 64 + j * 16 + lr];
#pragma unroll
  for (int i = 0; i < 4; ++i)
#pragma unroll
    for (int j = 0; j < 4; ++j) {
      int n = n0 + wn * 64 + j * 16 + lr;
#pragma unroll
      for (int r = 0; r < 4; ++r) {
        int m = m0 + wm * 64 + i * 16 + (l >> 4) * 4 + r;
        xp[(size_t)m * G3 + n] = (__hip_bfloat16)(acc[i][j][r] + bv[j]);
      }
    }
}

// ---------------------------------------------------------------------------
// Persistent GRU recurrence. Grid = 256 blocks: blockIdx.x = jt*16 + bt.
//   bt in [0,16): batch rows bt*16..+16  (group id; blocks with equal bt sync)
//   jt in [0,16): j-cols jt*32..+32 (x3 gates = 96 gate-cols)
// W slice (96x512 bf16) persists in LDS across all 128 steps.
// h state: fp32 in registers (2 per thread); bf16 h exchanged via global
// double buffer with per-group sense barriers (agent-scope atomics).
// Waves: (kh, ch) = K-half x col-half; 24 MFMA per wave per step.
// ---------------------------------------------------------------------------
__global__ __launch_bounds__(256, 1) void gru_persist(
    __hip_bfloat16* __restrict__ hbA, __hip_bfloat16* __restrict__ hbB,
    float* __restrict__ h32,
    const __hip_bfloat16* __restrict__ xp,   // [(b*SEQ+t)][1536] bf16
    const __hip_bfloat16* __restrict__ WrT,  // [1536][512] bf16
    const float* __restrict__ br,
    int* arrive, int* gen)
{
  extern __shared__ char smem[];
  __hip_bfloat16* W_s = (__hip_bfloat16*)smem;              // [96][520]  99,840 B
  __hip_bfloat16* h_s = (__hip_bfloat16*)(smem + 99840);    // [16][520]  16,640 B
  float*          red = (float*)(smem + 116480);            // [2][16][100] 12,800 B

  const int tid = threadIdx.x;
  const int bt = blockIdx.x & 15;     // group id (same-XCD under round-robin)
  const int jt = blockIdx.x >> 4;
  const int wave = tid >> 6, l = tid & 63;
  const int kh = wave & 1, ch = wave >> 1;
  const int lr = l & 15, lk = (l >> 4) * 8;

  // ---- one-time: stage Wr slice (96 rows x 512 k) ----
#pragma unroll
  for (int i = 0; i < 24; ++i) {
    int q = tid + i * 256;            // 0..6143 int4 chunks
    int row = q >> 6;                 // 0..95 = g*32 + jl
    int c = q & 63;
    int g = row >> 5, jl = row & 31;
    int n = g * HID + jt * 32 + jl;
    *(int4*)&W_s[row * 520 + c * 8] = *(const int4*)&WrT[(size_t)n * HID + c * 8];
  }

  // ---- per-thread epilogue ownership: (m, c) x p in {0,1} -> jl = c + p*16
  const int m = tid >> 4, c = tid & 15;
  const int b = bt * 16 + m;
  float brz[2], brr[2], brh[2], hreg[2];
#pragma unroll
  for (int p = 0; p < 2; ++p) {
    int j = jt * 32 + c + p * 16;
    brz[p] = br[j];
    brr[p] = br[HID + j];
    brh[p] = br[2 * HID + j];
    hreg[p] = 0.f;
  }
  __syncthreads();   // W_s ready (own block only)

  for (int t = 0; t < SEQ; ++t) {
    __hip_bfloat16* cur = (t & 1) ? hbB : hbA;
    __hip_bfloat16* nxt = (t & 1) ? hbA : hbB;

    // prefetch xp gate slices for this step (independent of h)
    float xzv[2], xrv[2], xhv[2];
    {
      size_t xbase = ((size_t)b * SEQ + t) * G3 + jt * 32 + c;
#pragma unroll
      for (int p = 0; p < 2; ++p) {
        xzv[p] = (float)xp[xbase + p * 16];
        xrv[p] = (float)xp[xbase + HID + p * 16];
        xhv[p] = (float)xp[xbase + 2 * HID + p * 16];
      }
    }

    // stage h rows (16 x 512 bf16 = 16 KB)
#pragma unroll
    for (int i = 0; i < 4; ++i) {
      int q = tid + i * 256;          // 0..1023
      int r = q >> 6, cc = q & 63;
      *(int4*)&h_s[r * 520 + cc * 8] =
          *(const int4*)&cur[(size_t)(bt * 16 + r) * HID + cc * 8];
    }
    __syncthreads();

    // MFMA: M=16, N=48 (this wave's col-half), K=256 (this wave's K-half)
    f32x4 acc[3] = {};
#pragma unroll
    for (int ks = 0; ks < 8; ++ks) {
      int k = kh * 256 + ks * 32 + lk;
      bf16x8 a = *(const bf16x8*)&h_s[lr * 520 + k];
#pragma unroll
      for (int f = 0; f < 3; ++f) {
        bf16x8 bfrag = *(const bf16x8*)&W_s[(ch * 48 + f * 16 + lr) * 520 + k];
        acc[f] = __builtin_amdgcn_mfma_f32_16x16x32_bf16(a, bfrag, acc[f], 0, 0, 0);
      }
    }
#pragma unroll
    for (int f = 0; f < 3; ++f)
#pragma unroll
      for (int i = 0; i < 4; ++i)
        red[kh * 1600 + ((l >> 4) * 4 + i) * 100 + ch * 48 + f * 16 + lr] = acc[f][i];
    __syncthreads();

    // epilogue: 2 outputs per thread
#pragma unroll
    for (int p = 0; p < 2; ++p) {
      int jl = c + p * 16;
      float rz = red[m * 100 + jl]      + red[1600 + m * 100 + jl];
      float rr = red[m * 100 + 32 + jl] + red[1600 + m * 100 + 32 + jl];
      float rh = red[m * 100 + 64 + jl] + red[1600 + m * 100 + 64 + jl];
      rz += brz[p];
      rr += brr[p];
      rh += brh[p];
      float z  = 1.f / (1.f + __expf(-(xzv[p] + rz)));
      float rg = 1.f / (1.f + __expf(-(xrv[p] + rr)));
      float hh = fmaxf(xhv[p] + rg * rh, 0.f);
      hreg[p] = z * hreg[p] + (1.f - z) * hh;
      nxt[(size_t)b * HID + jt * 32 + jl] = (__hip_bfloat16)hreg[p];
    }

    // group barrier (16 blocks sharing bt), skip after last step
    if (t < SEQ - 1) {
      __syncthreads();
      if (tid == 0) {
        __threadfence();
        int a = __hip_atomic_fetch_add(&arrive[bt], 1, __ATOMIC_ACQ_REL,
                                       __HIP_MEMORY_SCOPE_AGENT);
        if (a == 15) {
          __hip_atomic_store(&arrive[bt], 0, __ATOMIC_RELAXED,
                             __HIP_MEMORY_SCOPE_AGENT);
          __hip_atomic_store(&gen[bt], t + 1, __ATOMIC_RELEASE,
                             __HIP_MEMORY_SCOPE_AGENT);
        } else {
          while (__hip_atomic_load(&gen[bt], __ATOMIC_ACQUIRE,
                                   __HIP_MEMORY_SCOPE_AGENT) < t + 1)
            __builtin_amdgcn_s_sleep(2);
        }
      }
      __syncthreads();
    }
  }

  // final: dump fp32 h state
#pragma unroll
  for (int p = 0; p < 2; ++p)
    h32[(size_t)b * HID + jt * 32 + c + p * 16] = hreg[p];
}

// ---------------------------------------------------------------------------
// head: out[b] = h32[b][:] . Wd + bd
// ---------------------------------------------------------------------------
__global__ __launch_bounds__(64) void head_kernel(
    const float* __restrict__ h32, const float* __restrict__ Wd,
    const float* __restrict__ bd, float* __restrict__ out)
{
  int b = blockIdx.x, l = threadIdx.x;
  const float* hr = &h32[(size_t)b * HID];
  float s = 0.f;
#pragma unroll
  for (int i = 0; i < 8; ++i)
    s += hr[l + i * 64] * Wd[l + i * 64];
#pragma unroll
  for (int off = 32; off; off >>= 1) s += __shfl_down(s, off);
  if (l == 0) out[b] = s + bd[0];
}

// ---------------------------------------------------------------------------
extern "C" void kernel_launch(void* const* d_in, const int* in_sizes, int n_in,
                              void* d_out, int out_size, void* d_ws, size_t ws_size,
                              hipStream_t stream) {
  const float* x    = (const float*)d_in[0];
  const float* Wk   = (const float*)d_in[1];
  const float* Wr   = (const float*)d_in[2];
  const float* bias = (const float*)d_in[3];
  const float* Wd   = (const float*)d_in[4];
  const float* bd   = (const float*)d_in[5];
  float* out = (float*)d_out;

  char* ws = (char*)d_ws;
  size_t off = 0;
  __hip_bfloat16* xp  = (__hip_bfloat16*)(ws + off); off += (size_t)BATCH * SEQ * G3 * 2;
  __hip_bfloat16* xb  = (__hip_bfloat16*)(ws + off); off += (size_t)BATCH * SEQ * FEAT * 2;
  __hip_bfloat16* WkT = (__hip_bfloat16*)(ws + off); off += (size_t)G3 * FEAT * 2;
  __hip_bfloat16* WrT = (__hip_bfloat16*)(ws + off); off += (size_t)G3 * HID * 2;
  float*          h32 = (float*)(ws + off);          off += (size_t)BATCH * HID * 4;
  __hip_bfloat16* hb0 = (__hip_bfloat16*)(ws + off); off += (size_t)BATCH * HID * 2;
  __hip_bfloat16* hb1 = (__hip_bfloat16*)(ws + off); off += (size_t)BATCH * HID * 2;
  int*            arrive = (int*)(ws + off);         off += 16 * sizeof(int);
  int*            gen    = (int*)(ws + off);         off += 16 * sizeof(int);

  // converts / transposes
  convert_bf16<<<(BATCH * SEQ * FEAT) / (256 * 8), 256, 0, stream>>>(x, xb, BATCH * SEQ * FEAT);
  transpose_convert<<<dim3(G3 / 32, FEAT / 32), 256, 0, stream>>>(Wk, WkT);
  transpose_convert<<<dim3(G3 / 32, HID  / 32), 256, 0, stream>>>(Wr, WrT);

  // projection GEMM (bias folded in)
  proj_mfma<<<dim3(G3 / 128, (BATCH * SEQ) / 128), 256, 0, stream>>>(xb, WkT, bias, xp);

  // zero: h buffer for t=0, barrier state
  hipMemsetAsync(hb0, 0, (size_t)BATCH * HID * sizeof(__hip_bfloat16), stream);
  hipMemsetAsync(arrive, 0, 32 * sizeof(int), stream);

  // persistent recurrence (cooperative: all 256 blocks co-resident)
  const float* br = bias + G3;
  const size_t lds_bytes = 129280;
  hipFuncSetAttribute((const void*)gru_persist,
                      hipFuncAttributeMaxDynamicSharedMemorySize, (int)lds_bytes);
  {
    void* args[] = {(void*)&hb0, (void*)&hb1, (void*)&h32, (void*)&xp,
                    (void*)&WrT, (void*)&br, (void*)&arrive, (void*)&gen};
    hipLaunchCooperativeKernel((void*)gru_persist, dim3(256), dim3(256),
                               args, (unsigned)lds_bytes, stream);
  }

  head_kernel<<<256, 64, 0, stream>>>(h32, Wd, bd, out);
}

// Round 4
// 764.003 us; speedup vs baseline: 5.1476x; 5.1476x over previous
//
#include <hip/hip_runtime.h>
#include <hip/hip_bf16.h>
#include <math.h>

constexpr int BATCH = 256;
constexpr int SEQ   = 128;
constexpr int FEAT  = 512;
constexpr int HID   = 512;
constexpr int G3    = 1536;

typedef __bf16 bf16x8 __attribute__((ext_vector_type(8)));
typedef float  f32x4  __attribute__((ext_vector_type(4)));

// ---------------------------------------------------------------------------
// fp32 -> bf16 convert (vectorized, 8/thread)
// ---------------------------------------------------------------------------
__global__ __launch_bounds__(256) void convert_bf16(
    const float* __restrict__ in, __hip_bfloat16* __restrict__ out, int n)
{
  int i = (blockIdx.x * 256 + threadIdx.x) * 8;
  if (i >= n) return;
  float4 v0 = *(const float4*)&in[i];
  float4 v1 = *(const float4*)&in[i + 4];
  __hip_bfloat16 o[8];
  o[0] = (__hip_bfloat16)v0.x; o[1] = (__hip_bfloat16)v0.y;
  o[2] = (__hip_bfloat16)v0.z; o[3] = (__hip_bfloat16)v0.w;
  o[4] = (__hip_bfloat16)v1.x; o[5] = (__hip_bfloat16)v1.y;
  o[6] = (__hip_bfloat16)v1.z; o[7] = (__hip_bfloat16)v1.w;
  *(int4*)&out[i] = *(int4*)o;
}

// ---------------------------------------------------------------------------
// transpose + convert: in[512][1536] f32 -> outT[1536][512] bf16
// ---------------------------------------------------------------------------
__global__ __launch_bounds__(256) void transpose_convert(
    const float* __restrict__ in, __hip_bfloat16* __restrict__ outT)
{
  __shared__ float tile[32][33];
  const int c0 = blockIdx.x * 32;
  const int r0 = blockIdx.y * 32;
  const int tid = threadIdx.x;
  {
    int row = tid >> 3, c4 = tid & 7;
    float4 v = *(const float4*)&in[(size_t)(r0 + row) * G3 + c0 + c4 * 4];
    tile[row][c4 * 4 + 0] = v.x;
    tile[row][c4 * 4 + 1] = v.y;
    tile[row][c4 * 4 + 2] = v.z;
    tile[row][c4 * 4 + 3] = v.w;
  }
  __syncthreads();
  {
    int rowT = tid >> 3, c4 = tid & 7;
    __hip_bfloat16 o[4];
#pragma unroll
    for (int e = 0; e < 4; ++e)
      o[e] = (__hip_bfloat16)tile[c4 * 4 + e][rowT];
    *(int2*)&outT[(size_t)(c0 + rowT) * FEAT + r0 + c4 * 4] = *(int2*)o;
  }
}

// ---------------------------------------------------------------------------
// proj: xp[m][n] (bf16) = xb[m][:] @ Wk[:, n] + bi[n]
// 128x128 tile, BK=64. Staging via global_load_lds (16B), linear LDS with
// XOR swizzle: LDS chunk p of row r holds global chunk (p ^ (r&7)).
// ---------------------------------------------------------------------------
__global__ __launch_bounds__(256) void proj_mfma(
    const __hip_bfloat16* __restrict__ xb, const __hip_bfloat16* __restrict__ WkT,
    const float* __restrict__ bias, __hip_bfloat16* __restrict__ xp)
{
  __shared__ __align__(16) __hip_bfloat16 As[128 * 64];  // 16 KB, linear
  __shared__ __align__(16) __hip_bfloat16 Bs[128 * 64];

  const int tid = threadIdx.x;
  const int wave = tid >> 6, l = tid & 63;
  const int wm = wave >> 1, wn = wave & 1;
  const int m0 = blockIdx.y * 128;
  const int n0 = blockIdx.x * 128;
  const int lr = l & 15, lh = l >> 4;
  const int swz = lr & 7;             // frag-read swizzle (= row&7)

  const int srow = l >> 3;            // staging: row within 8-row group
  const int schk = l & 7;             // staging: 16B chunk, pre-swizzled source
  const int wrow = wave * 32;         // this wave's 32 rows of the 128-row tile

  f32x4 acc[4][4] = {};

  for (int k0 = 0; k0 < FEAT; k0 += 64) {
    __syncthreads();
#pragma unroll
    for (int i = 0; i < 4; ++i) {
      int r = wrow + i * 8 + srow;    // tile row; r&7 == srow
      const __hip_bfloat16* srcA = &xb[(size_t)(m0 + r) * FEAT + k0 + ((schk ^ srow) * 8)];
      __builtin_amdgcn_global_load_lds(
          (const __attribute__((address_space(1))) void*)srcA,
          (__attribute__((address_space(3))) void*)&As[(wrow + i * 8) * 64], 16, 0, 0);
    }
#pragma unroll
    for (int i = 0; i < 4; ++i) {
      int r = wrow + i * 8 + srow;
      const __hip_bfloat16* srcB = &WkT[(size_t)(n0 + r) * FEAT + k0 + ((schk ^ srow) * 8)];
      __builtin_amdgcn_global_load_lds(
          (const __attribute__((address_space(1))) void*)srcB,
          (__attribute__((address_space(3))) void*)&Bs[(wrow + i * 8) * 64], 16, 0, 0);
    }
    __syncthreads();

#pragma unroll
    for (int ks = 0; ks < 2; ++ks) {
      bf16x8 a[4], b[4];
#pragma unroll
      for (int i = 0; i < 4; ++i) {
        int row = wm * 64 + i * 16 + lr;
        a[i] = *(const bf16x8*)&As[row * 64 + (((ks * 4 + lh) ^ swz) * 8)];
      }
#pragma unroll
      for (int j = 0; j < 4; ++j) {
        int row = wn * 64 + j * 16 + lr;
        b[j] = *(const bf16x8*)&Bs[row * 64 + (((ks * 4 + lh) ^ swz) * 8)];
      }
#pragma unroll
      for (int i = 0; i < 4; ++i)
#pragma unroll
        for (int j = 0; j < 4; ++j)
          acc[i][j] = __builtin_amdgcn_mfma_f32_16x16x32_bf16(a[i], b[j], acc[i][j], 0, 0, 0);
    }
  }

  float bv[4];
#pragma unroll
  for (int j = 0; j < 4; ++j)
    bv[j] = bias[n0 + wn * 64 + j * 16 + lr];
#pragma unroll
  for (int i = 0; i < 4; ++i)
#pragma unroll
    for (int j = 0; j < 4; ++j) {
      int n = n0 + wn * 64 + j * 16 + lr;
#pragma unroll
      for (int r = 0; r < 4; ++r) {
        int m = m0 + wm * 64 + i * 16 + lh * 4 + r;
        xp[(size_t)m * G3 + n] = (__hip_bfloat16)(acc[i][j][r] + bv[j]);
      }
    }
}

// ---------------------------------------------------------------------------
// One GRU step. M=32 rows per block, 16 j-cols (x3 gates = 48 n-cols).
// Grid (32 jt, 8 bt) = 256 blocks. 4 waves split K=512 by 128 each.
// W fragments load DIRECTLY global->VGPR (L2-resident WrT, reuse x2 via two
// M-tiles). Only h staged in LDS. Cross-wave LDS reduction, then epilogue.
// ---------------------------------------------------------------------------
__global__ __launch_bounds__(256) void gru_step2(
    const __hip_bfloat16* __restrict__ hb_in, __hip_bfloat16* __restrict__ hb_out,
    float* __restrict__ h32,
    const __hip_bfloat16* __restrict__ xp,   // [(b*SEQ+t)][1536] bf16 (bias incl.)
    const __hip_bfloat16* __restrict__ WrT,  // [1536][512] bf16
    const float* __restrict__ br, int t)
{
  __shared__ __align__(16) __hip_bfloat16 h_s[32][520];  // 33.3 KB
  __shared__ float red[4][32][49];                        // 25.1 KB

  const int tid = threadIdx.x;
  const int wave = tid >> 6, l = tid & 63;
  const int jt = blockIdx.x;        // 0..31 -> j-cols jt*16..+16
  const int m0g = blockIdx.y * 32;  // batch rows

  // stage h: 32 rows x 512 bf16 = 2048 int4, 8/thread (coalesced)
#pragma unroll
  for (int i = 0; i < 8; ++i) {
    int q = tid + i * 256;
    int r = q >> 6, c = q & 63;
    *(int4*)&h_s[r][c * 8] = *(const int4*)&hb_in[(size_t)(m0g + r) * HID + c * 8];
  }

  // early-issue epilogue operands (independent of h)
  const int em = tid >> 4, ec = tid & 15;   // epilogue (row, col) for p=0; p=1 adds 16 rows
  float xzv[2], xrv[2], xhv[2], holdv[2], brz, brr, brh;
  {
    int j = jt * 16 + ec;
    brz = br[j]; brr = br[HID + j]; brh = br[2 * HID + j];
#pragma unroll
    for (int p = 0; p < 2; ++p) {
      int b = m0g + em + p * 16;
      size_t xbase = ((size_t)b * SEQ + t) * G3 + j;
      xzv[p] = (float)xp[xbase];
      xrv[p] = (float)xp[xbase + HID];
      xhv[p] = (float)xp[xbase + 2 * HID];
      holdv[p] = h32[(size_t)b * HID + j];
    }
  }
  __syncthreads();

  // MFMA: this wave's K-slice [wave*128, +128), M=32 (2 tiles), N=48 (3 gates)
  const int lr = l & 15, lh = l >> 4;
  f32x4 acc0[3] = {}, acc1[3] = {};
  const size_t wb = (size_t)(jt * 16 + lr) * HID + wave * 128 + lh * 8;
#pragma unroll
  for (int s = 0; s < 4; ++s) {
    int k = wave * 128 + s * 32 + lh * 8;
    bf16x8 a0 = *(const bf16x8*)&h_s[lr][k];
    bf16x8 a1 = *(const bf16x8*)&h_s[16 + lr][k];
#pragma unroll
    for (int g = 0; g < 3; ++g) {
      bf16x8 bf = *(const bf16x8*)&WrT[wb + (size_t)g * HID * HID + s * 32];
      acc0[g] = __builtin_amdgcn_mfma_f32_16x16x32_bf16(a0, bf, acc0[g], 0, 0, 0);
      acc1[g] = __builtin_amdgcn_mfma_f32_16x16x32_bf16(a1, bf, acc1[g], 0, 0, 0);
    }
  }

  // per-wave partials -> LDS   (C map: col=lane&15, row=(lane>>4)*4+reg)
#pragma unroll
  for (int g = 0; g < 3; ++g)
#pragma unroll
    for (int i = 0; i < 4; ++i) {
      red[wave][lh * 4 + i][g * 16 + lr]      = acc0[g][i];
      red[wave][16 + lh * 4 + i][g * 16 + lr] = acc1[g][i];
    }
  __syncthreads();

  // epilogue: 2 outputs per thread (rows em, em+16)
#pragma unroll
  for (int p = 0; p < 2; ++p) {
    int m = em + p * 16;
    int b = m0g + m, j = jt * 16 + ec;
    float rz = red[0][m][ec]      + red[1][m][ec]      + red[2][m][ec]      + red[3][m][ec];
    float rr = red[0][m][16 + ec] + red[1][m][16 + ec] + red[2][m][16 + ec] + red[3][m][16 + ec];
    float rh = red[0][m][32 + ec] + red[1][m][32 + ec] + red[2][m][32 + ec] + red[3][m][32 + ec];
    rz += brz; rr += brr; rh += brh;

    float z  = 1.f / (1.f + __expf(-(xzv[p] + rz)));
    float rg = 1.f / (1.f + __expf(-(xrv[p] + rr)));
    float hh = fmaxf(xhv[p] + rg * rh, 0.f);
    float hnew = z * holdv[p] + (1.f - z) * hh;

    h32[(size_t)b * HID + j] = hnew;
    hb_out[(size_t)b * HID + j] = (__hip_bfloat16)hnew;
  }
}

// ---------------------------------------------------------------------------
// head: out[b] = h32[b][:] . Wd + bd
// ---------------------------------------------------------------------------
__global__ __launch_bounds__(64) void head_kernel(
    const float* __restrict__ h32, const float* __restrict__ Wd,
    const float* __restrict__ bd, float* __restrict__ out)
{
  int b = blockIdx.x, l = threadIdx.x;
  const float* hr = &h32[(size_t)b * HID];
  float s = 0.f;
#pragma unroll
  for (int i = 0; i < 8; ++i)
    s += hr[l + i * 64] * Wd[l + i * 64];
#pragma unroll
  for (int off = 32; off; off >>= 1) s += __shfl_down(s, off);
  if (l == 0) out[b] = s + bd[0];
}

// ---------------------------------------------------------------------------
extern "C" void kernel_launch(void* const* d_in, const int* in_sizes, int n_in,
                              void* d_out, int out_size, void* d_ws, size_t ws_size,
                              hipStream_t stream) {
  const float* x    = (const float*)d_in[0];
  const float* Wk   = (const float*)d_in[1];
  const float* Wr   = (const float*)d_in[2];
  const float* bias = (const float*)d_in[3];
  const float* Wd   = (const float*)d_in[4];
  const float* bd   = (const float*)d_in[5];
  float* out = (float*)d_out;

  char* ws = (char*)d_ws;
  size_t off = 0;
  __hip_bfloat16* xp  = (__hip_bfloat16*)(ws + off); off += (size_t)BATCH * SEQ * G3 * 2;
  __hip_bfloat16* xb  = (__hip_bfloat16*)(ws + off); off += (size_t)BATCH * SEQ * FEAT * 2;
  __hip_bfloat16* WkT = (__hip_bfloat16*)(ws + off); off += (size_t)G3 * FEAT * 2;
  __hip_bfloat16* WrT = (__hip_bfloat16*)(ws + off); off += (size_t)G3 * HID * 2;
  float*          h32 = (float*)(ws + off);          off += (size_t)BATCH * HID * 4;
  __hip_bfloat16* hb0 = (__hip_bfloat16*)(ws + off); off += (size_t)BATCH * HID * 2;
  __hip_bfloat16* hb1 = (__hip_bfloat16*)(ws + off); off += (size_t)BATCH * HID * 2;

  // converts / transposes
  convert_bf16<<<(BATCH * SEQ * FEAT) / (256 * 8), 256, 0, stream>>>(x, xb, BATCH * SEQ * FEAT);
  transpose_convert<<<dim3(G3 / 32, FEAT / 32), 256, 0, stream>>>(Wk, WkT);
  transpose_convert<<<dim3(G3 / 32, HID  / 32), 256, 0, stream>>>(Wr, WrT);

  // projection GEMM (bias folded in)
  proj_mfma<<<dim3(G3 / 128, (BATCH * SEQ) / 128), 256, 0, stream>>>(xb, WkT, bias, xp);

  // zero h state (h32 read at t=0; harness does not re-poison between replays)
  hipMemsetAsync(h32, 0, (size_t)BATCH * HID * sizeof(float), stream);
  hipMemsetAsync(hb0, 0, (size_t)BATCH * HID * sizeof(__hip_bfloat16), stream);

  const float* br = bias + G3;
  for (int t = 0; t < SEQ; ++t) {
    const __hip_bfloat16* hin = (t & 1) ? hb1 : hb0;
    __hip_bfloat16*      hout = (t & 1) ? hb0 : hb1;
    gru_step2<<<dim3(32, 8), 256, 0, stream>>>(hin, hout, h32, xp, WrT, br, t);
  }

  head_kernel<<<256, 64, 0, stream>>>(h32, Wd, bd, out);
}